// Round 2
// baseline (16.966 us; speedup 1.0000x reference)
//
#include <hip/hip_runtime.h>

// Fused model kernel for MI355X (gfx950) — round 2.
//
// Reference collapse: the RNN scan's carry is out = lin2(x_t) + b2 —
// independent of the previous carry -> only the LAST timestep (s = S-1)
// matters. Read xs[r, S-1, b, :] only (5 MB instead of 335 MB).
//
// Round-2 change: NO LDS. All weight/bias reads use compile-time-constant
// indices off the global kernel-arg pointers; hipcc proves them wave-uniform
// and emits s_load_* into SGPRs (scalar cache). Each FMA is
// v_fma_f32 v, s, v (1 SGPR read per VALU inst — allowed). This removes the
// global->LDS->barrier chain and ~168 ds_read_b128 broadcasts per thread.

#define RCELLS 5

__global__ __launch_bounds__(256) void fused_model_kernel(
    const float* __restrict__ x0,
    const float* __restrict__ xs,
    const float* __restrict__ rnn_w2,
    const float* __restrict__ rnn_b2,
    const float* __restrict__ w1,
    const float* __restrict__ b1,
    const float* __restrict__ w2,
    const float* __restrict__ b2,
    const float* __restrict__ w3,
    const float* __restrict__ b3,
    float* __restrict__ out,
    int B,
    long long sB2,      // S * B * 2   (stride between rnn cells in xs)
    long long lastOff)  // (S-1) * B * 2
{
    const int b = blockIdx.x * 256 + threadIdx.x;
    if (b >= B) return;

    // ---- build the 16-wide input vector ----
    float x[16];
    {
        const float2* p = reinterpret_cast<const float2*>(x0 + (size_t)b * 6);
        float2 a = p[0], c = p[1], d = p[2];
        x[0] = a.x; x[1] = a.y; x[2] = c.x; x[3] = c.y; x[4] = d.x; x[5] = d.y;
    }
#pragma unroll
    for (int r = 0; r < RCELLS; ++r) {
        const float2 xt = *reinterpret_cast<const float2*>(
            xs + (size_t)r * sB2 + lastOff + (size_t)b * 2);
        // rnn_w2[r] is row-major [2][2]; constant indices -> s_load
        x[6 + 2 * r] = fmaf(xt.x, rnn_w2[r * 4 + 0],
                       fmaf(xt.y, rnn_w2[r * 4 + 1], rnn_b2[r * 2 + 0]));
        x[7 + 2 * r] = fmaf(xt.x, rnn_w2[r * 4 + 2],
                       fmaf(xt.y, rnn_w2[r * 4 + 3], rnn_b2[r * 2 + 1]));
    }

    // ---- layer 1: h1 = relu(x @ w1.T + b1) ----
    float h1[16];
#pragma unroll
    for (int o = 0; o < 16; ++o) {
        float acc = b1[o];
#pragma unroll
        for (int k = 0; k < 16; ++k)
            acc = fmaf(x[k], w1[o * 16 + k], acc);
        h1[o] = fmaxf(acc, 0.0f);
    }

    // ---- layer 2: h2 = relu(h1 @ w2.T + b2) ----
    float h2[16];
#pragma unroll
    for (int o = 0; o < 16; ++o) {
        float acc = b2[o];
#pragma unroll
        for (int k = 0; k < 16; ++k)
            acc = fmaf(h1[k], w2[o * 16 + k], acc);
        h2[o] = fmaxf(acc, 0.0f);
    }

    // ---- logits: lg = h2 @ w3.T + b3 ----
    float lg[10];
#pragma unroll
    for (int o = 0; o < 10; ++o) {
        float acc = b3[o];
#pragma unroll
        for (int k = 0; k < 16; ++k)
            acc = fmaf(h2[k], w3[o * 16 + k], acc);
        lg[o] = acc;
    }

    // ---- grouped softmax: [0:2], [2:6], [6:10] ----
    float p[10];
    {
        float m = fmaxf(lg[0], lg[1]);
        float e0 = __expf(lg[0] - m), e1 = __expf(lg[1] - m);
        float inv = 1.0f / (e0 + e1);
        p[0] = e0 * inv; p[1] = e1 * inv;
    }
    {
        float m = fmaxf(fmaxf(lg[2], lg[3]), fmaxf(lg[4], lg[5]));
        float e2 = __expf(lg[2] - m), e3 = __expf(lg[3] - m);
        float e4 = __expf(lg[4] - m), e5 = __expf(lg[5] - m);
        float inv = 1.0f / (e2 + e3 + e4 + e5);
        p[2] = e2 * inv; p[3] = e3 * inv; p[4] = e4 * inv; p[5] = e5 * inv;
    }
    {
        float m = fmaxf(fmaxf(lg[6], lg[7]), fmaxf(lg[8], lg[9]));
        float e6 = __expf(lg[6] - m), e7 = __expf(lg[7] - m);
        float e8 = __expf(lg[8] - m), e9 = __expf(lg[9] - m);
        float inv = 1.0f / (e6 + e7 + e8 + e9);
        p[6] = e6 * inv; p[7] = e7 * inv; p[8] = e8 * inv; p[9] = e9 * inv;
    }

    // ---- store (b*10 floats = 40B, 8B-aligned -> 5x float2) ----
    float2* po = reinterpret_cast<float2*>(out + (size_t)b * 10);
    po[0] = make_float2(p[0], p[1]);
    po[1] = make_float2(p[2], p[3]);
    po[2] = make_float2(p[4], p[5]);
    po[3] = make_float2(p[6], p[7]);
    po[4] = make_float2(p[8], p[9]);
}

extern "C" void kernel_launch(void* const* d_in, const int* in_sizes, int n_in,
                              void* d_out, int out_size, void* d_ws, size_t ws_size,
                              hipStream_t stream) {
    const float* x0     = (const float*)d_in[0];
    const float* xs     = (const float*)d_in[1];
    // d_in[2] = rnn_w1, d_in[3] = rnn_b1 -- dead code in the reference (DCE'd)
    const float* rnn_w2 = (const float*)d_in[4];
    const float* rnn_b2 = (const float*)d_in[5];
    const float* w1     = (const float*)d_in[6];
    const float* b1     = (const float*)d_in[7];
    const float* w2     = (const float*)d_in[8];
    const float* b2     = (const float*)d_in[9];
    const float* w3     = (const float*)d_in[10];
    const float* b3     = (const float*)d_in[11];

    const int B = in_sizes[0] / 6;                    // x0 is [B, 6]
    const int S = in_sizes[1] / (RCELLS * 2 * B);     // xs is [R, S, B, 2]
    const long long sB2     = (long long)S * B * 2;
    const long long lastOff = (long long)(S - 1) * B * 2;

    const int grid = (B + 255) / 256;
    fused_model_kernel<<<grid, 256, 0, stream>>>(
        x0, xs, rnn_w2, rnn_b2, w1, b1, w2, b2, w3, b3,
        (float*)d_out, B, sB2, lastOff);
}

// Round 3
// 16.429 us; speedup vs baseline: 1.0327x; 1.0327x over previous
//
#include <hip/hip_runtime.h>

// Fused model kernel for MI355X (gfx950) — round 3.
//
// Reference collapse: the RNN scan's carry is out = lin2(x_t) + b2 —
// independent of the previous carry -> only the LAST timestep matters.
// Read xs[r, S-1, b, :] only (5 MB instead of 335 MB).
//
// Round-3 change: ROWS=2 per thread (rows b and b+256, both coalesced).
// Each LDS weight float4 is read ONCE and feeds TWO rows' FMA chains:
// halves the per-CU LDS broadcast instruction count (the R1 bottleneck),
// and the 2 independent accumulator chains give ILP to cover LDS latency
// at the reduced (1 wave/SIMD) occupancy.

#define RCELLS 5

__global__ __launch_bounds__(256) void fused_model_kernel(
    const float* __restrict__ x0,
    const float* __restrict__ xs,
    const float* __restrict__ rnn_w2,
    const float* __restrict__ rnn_b2,
    const float* __restrict__ w1,
    const float* __restrict__ b1,
    const float* __restrict__ w2,
    const float* __restrict__ b2,
    const float* __restrict__ w3,
    const float* __restrict__ b3,
    float* __restrict__ out,
    int B,
    long long sB2,      // S * B * 2   (stride between rnn cells in xs)
    long long lastOff)  // (S-1) * B * 2
{
    // LDS layout (floats), 16B-aligned segments:
    //   [0,256)   w1      [256,512) w2       [512,672) w3
    //   [672,688) b1      [688,704) b2       [704,714) b3
    //   [720,740) rnn_w2  [740,750) rnn_b2
    __shared__ __align__(16) float sm[768];
    const int t = threadIdx.x;

    sm[t]       = w1[t];          // blockDim == 256 exactly
    sm[256 + t] = w2[t];
    if (t < 160) sm[512 + t] = w3[t];
    if (t < 16) { sm[672 + t] = b1[t]; sm[688 + t] = b2[t]; }
    if (t < 20) sm[720 + t] = rnn_w2[t];
    if (t < 10) { sm[704 + t] = b3[t]; sm[740 + t] = rnn_b2[t]; }
    __syncthreads();

    const int b0 = blockIdx.x * 512 + t;   // row A
    const int b1r = b0 + 256;              // row B (coalesced with row A's wave)
    if (b1r >= B + 256) return;            // B divisible by 512 in practice

    // ---- build the two 16-wide input vectors ----
    float x[2][16];
    {
        const float2* pa = reinterpret_cast<const float2*>(x0 + (size_t)b0 * 6);
        const float2* pb = reinterpret_cast<const float2*>(x0 + (size_t)b1r * 6);
        float2 a0 = pa[0], a1 = pa[1], a2 = pa[2];
        float2 c0 = pb[0], c1 = pb[1], c2 = pb[2];
        x[0][0] = a0.x; x[0][1] = a0.y; x[0][2] = a1.x;
        x[0][3] = a1.y; x[0][4] = a2.x; x[0][5] = a2.y;
        x[1][0] = c0.x; x[1][1] = c0.y; x[1][2] = c1.x;
        x[1][3] = c1.y; x[1][4] = c2.x; x[1][5] = c2.y;
    }
#pragma unroll
    for (int r = 0; r < RCELLS; ++r) {
        const float2 xa = *reinterpret_cast<const float2*>(
            xs + (size_t)r * sB2 + lastOff + (size_t)b0 * 2);
        const float2 xb = *reinterpret_cast<const float2*>(
            xs + (size_t)r * sB2 + lastOff + (size_t)b1r * 2);
        const float rw0 = sm[720 + r * 4 + 0], rw1 = sm[720 + r * 4 + 1];
        const float rw2 = sm[720 + r * 4 + 2], rw3 = sm[720 + r * 4 + 3];
        const float rb0 = sm[740 + r * 2 + 0], rb1 = sm[740 + r * 2 + 1];
        x[0][6 + 2 * r] = fmaf(xa.x, rw0, fmaf(xa.y, rw1, rb0));
        x[0][7 + 2 * r] = fmaf(xa.x, rw2, fmaf(xa.y, rw3, rb1));
        x[1][6 + 2 * r] = fmaf(xb.x, rw0, fmaf(xb.y, rw1, rb0));
        x[1][7 + 2 * r] = fmaf(xb.x, rw2, fmaf(xb.y, rw3, rb1));
    }

    const float4* w1v = reinterpret_cast<const float4*>(sm);
    const float4* w2v = reinterpret_cast<const float4*>(sm + 256);
    const float4* w3v = reinterpret_cast<const float4*>(sm + 512);

    // ---- layer 1 ----
    float h1[2][16];
#pragma unroll
    for (int o = 0; o < 16; ++o) {
        float a0 = sm[672 + o], a1 = a0;
#pragma unroll
        for (int k = 0; k < 4; ++k) {
            float4 w = w1v[o * 4 + k];
            a0 = fmaf(x[0][4 * k + 0], w.x, a0);
            a1 = fmaf(x[1][4 * k + 0], w.x, a1);
            a0 = fmaf(x[0][4 * k + 1], w.y, a0);
            a1 = fmaf(x[1][4 * k + 1], w.y, a1);
            a0 = fmaf(x[0][4 * k + 2], w.z, a0);
            a1 = fmaf(x[1][4 * k + 2], w.z, a1);
            a0 = fmaf(x[0][4 * k + 3], w.w, a0);
            a1 = fmaf(x[1][4 * k + 3], w.w, a1);
        }
        h1[0][o] = fmaxf(a0, 0.0f);
        h1[1][o] = fmaxf(a1, 0.0f);
    }

    // ---- layer 2 ----
    float h2[2][16];
#pragma unroll
    for (int o = 0; o < 16; ++o) {
        float a0 = sm[688 + o], a1 = a0;
#pragma unroll
        for (int k = 0; k < 4; ++k) {
            float4 w = w2v[o * 4 + k];
            a0 = fmaf(h1[0][4 * k + 0], w.x, a0);
            a1 = fmaf(h1[1][4 * k + 0], w.x, a1);
            a0 = fmaf(h1[0][4 * k + 1], w.y, a0);
            a1 = fmaf(h1[1][4 * k + 1], w.y, a1);
            a0 = fmaf(h1[0][4 * k + 2], w.z, a0);
            a1 = fmaf(h1[1][4 * k + 2], w.z, a1);
            a0 = fmaf(h1[0][4 * k + 3], w.w, a0);
            a1 = fmaf(h1[1][4 * k + 3], w.w, a1);
        }
        h2[0][o] = fmaxf(a0, 0.0f);
        h2[1][o] = fmaxf(a1, 0.0f);
    }

    // ---- logits ----
    float lg[2][10];
#pragma unroll
    for (int o = 0; o < 10; ++o) {
        float a0 = sm[704 + o], a1 = a0;
#pragma unroll
        for (int k = 0; k < 4; ++k) {
            float4 w = w3v[o * 4 + k];
            a0 = fmaf(h2[0][4 * k + 0], w.x, a0);
            a1 = fmaf(h2[1][4 * k + 0], w.x, a1);
            a0 = fmaf(h2[0][4 * k + 1], w.y, a0);
            a1 = fmaf(h2[1][4 * k + 1], w.y, a1);
            a0 = fmaf(h2[0][4 * k + 2], w.z, a0);
            a1 = fmaf(h2[1][4 * k + 2], w.z, a1);
            a0 = fmaf(h2[0][4 * k + 3], w.w, a0);
            a1 = fmaf(h2[1][4 * k + 3], w.w, a1);
        }
        lg[0][o] = a0;
        lg[1][o] = a1;
    }

    // ---- grouped softmax + store, per row ----
#pragma unroll
    for (int rr = 0; rr < 2; ++rr) {
        float p[10];
        {
            float m = fmaxf(lg[rr][0], lg[rr][1]);
            float e0 = __expf(lg[rr][0] - m), e1 = __expf(lg[rr][1] - m);
            float inv = 1.0f / (e0 + e1);
            p[0] = e0 * inv; p[1] = e1 * inv;
        }
        {
            float m = fmaxf(fmaxf(lg[rr][2], lg[rr][3]), fmaxf(lg[rr][4], lg[rr][5]));
            float e2 = __expf(lg[rr][2] - m), e3 = __expf(lg[rr][3] - m);
            float e4 = __expf(lg[rr][4] - m), e5 = __expf(lg[rr][5] - m);
            float inv = 1.0f / (e2 + e3 + e4 + e5);
            p[2] = e2 * inv; p[3] = e3 * inv; p[4] = e4 * inv; p[5] = e5 * inv;
        }
        {
            float m = fmaxf(fmaxf(lg[rr][6], lg[rr][7]), fmaxf(lg[rr][8], lg[rr][9]));
            float e6 = __expf(lg[rr][6] - m), e7 = __expf(lg[rr][7] - m);
            float e8 = __expf(lg[rr][8] - m), e9 = __expf(lg[rr][9] - m);
            float inv = 1.0f / (e6 + e7 + e8 + e9);
            p[6] = e6 * inv; p[7] = e7 * inv; p[8] = e8 * inv; p[9] = e9 * inv;
        }
        const int brow = (rr == 0) ? b0 : b1r;
        float2* po = reinterpret_cast<float2*>(out + (size_t)brow * 10);
        po[0] = make_float2(p[0], p[1]);
        po[1] = make_float2(p[2], p[3]);
        po[2] = make_float2(p[4], p[5]);
        po[3] = make_float2(p[6], p[7]);
        po[4] = make_float2(p[8], p[9]);
    }
}

extern "C" void kernel_launch(void* const* d_in, const int* in_sizes, int n_in,
                              void* d_out, int out_size, void* d_ws, size_t ws_size,
                              hipStream_t stream) {
    const float* x0     = (const float*)d_in[0];
    const float* xs     = (const float*)d_in[1];
    // d_in[2] = rnn_w1, d_in[3] = rnn_b1 -- dead code in the reference (DCE'd)
    const float* rnn_w2 = (const float*)d_in[4];
    const float* rnn_b2 = (const float*)d_in[5];
    const float* w1     = (const float*)d_in[6];
    const float* b1     = (const float*)d_in[7];
    const float* w2     = (const float*)d_in[8];
    const float* b2     = (const float*)d_in[9];
    const float* w3     = (const float*)d_in[10];
    const float* b3     = (const float*)d_in[11];

    const int B = in_sizes[0] / 6;                    // x0 is [B, 6]
    const int S = in_sizes[1] / (RCELLS * 2 * B);     // xs is [R, S, B, 2]
    const long long sB2     = (long long)S * B * 2;
    const long long lastOff = (long long)(S - 1) * B * 2;

    const int grid = (B + 511) / 512;                 // 2 rows per thread
    fused_model_kernel<<<grid, 256, 0, stream>>>(
        x0, xs, rnn_w2, rnn_b2, w1, b1, w2, b2, w3, b3,
        (float*)d_out, B, sB2, lastOff);
}

// Round 4
// 10.168 us; speedup vs baseline: 1.6685x; 1.6158x over previous
//
#include <hip/hip_runtime.h>

// Fused model kernel for MI355X (gfx950) — round 4: MFMA formulation.
//
// Reference collapse: the RNN carry is out = lin2(x_t) + b2 (independent of
// previous carry) -> only the last timestep matters. Read xs[r,S-1,b,:] only.
//
// MLP via v_mfma_f32_16x16x16_f16, computing transposed activations
// T = W * X^T + b (features x batch). Key layout identity (m89-verified
// C/D: col=lane&15, row=4*(lane>>4)+reg; standard A/B: A row=lane&15
// k=4*(lane>>4)+i, B col=lane&15 k=4*(lane>>4)+i):
//     D layout == B layout  =>  relu(D) feeds the next MFMA's B operand
// with zero cross-lane movement. Weights live in 3 persistent A-fragments.
// Per 16-row tile: 3 MFMA + ~20 VALU (vs ~770 FMA + 168 LDS reads before).
//
// Occupancy: 2 tiles/wave -> 128 rows/block -> 1024 blocks = 4 blocks/CU
// = 4 waves/SIMD (2x the scalar kernel's TLP), tiny serial chain per wave.

#define RCELLS 5
#define TILES  2   // 16-row MFMA tiles per wave

typedef _Float16 half4 __attribute__((ext_vector_type(4)));
typedef float    f32x4 __attribute__((ext_vector_type(4)));

__global__ __launch_bounds__(256, 4) void fused_model_mfma(
    const float* __restrict__ x0,
    const float* __restrict__ xs,
    const float* __restrict__ rnn_w2,
    const float* __restrict__ rnn_b2,
    const float* __restrict__ w1,
    const float* __restrict__ b1,
    const float* __restrict__ w2,
    const float* __restrict__ b2,
    const float* __restrict__ w3,
    const float* __restrict__ b3,
    float* __restrict__ out,
    int B,
    long long sB2,      // S * B * 2   (stride between rnn cells in xs)
    long long lastOff)  // (S-1) * B * 2
{
    const int tid  = threadIdx.x;
    const int wid  = tid >> 6;
    const int lane = tid & 63;
    const int g    = lane >> 4;   // k-slice group (0..3)
    const int q    = lane & 15;   // row (A) / col (B,D) index
    const int base = blockIdx.x * (TILES * 16 * 4) + wid * (TILES * 16);

    // Per-wave logits scratch: [TILES][16 rows][20 floats] (pad 20 -> all
    // float4 accesses 16B-aligned, worst LDS conflict 8-way on a one-shot read)
    __shared__ float sm[4 * TILES * 16 * 20];

    // ---- persistent weight A-fragments: A[row=q][k=4g+i] ----
    half4 w1f, w2f, w3f;
    {
        float4 w = *reinterpret_cast<const float4*>(w1 + q * 16 + 4 * g);
        w1f[0] = (_Float16)w.x; w1f[1] = (_Float16)w.y;
        w1f[2] = (_Float16)w.z; w1f[3] = (_Float16)w.w;
        w = *reinterpret_cast<const float4*>(w2 + q * 16 + 4 * g);
        w2f[0] = (_Float16)w.x; w2f[1] = (_Float16)w.y;
        w2f[2] = (_Float16)w.z; w2f[3] = (_Float16)w.w;
        if (q < 10) {
            w = *reinterpret_cast<const float4*>(w3 + q * 16 + 4 * g);
            w3f[0] = (_Float16)w.x; w3f[1] = (_Float16)w.y;
            w3f[2] = (_Float16)w.z; w3f[3] = (_Float16)w.w;
        } else {
            w3f[0] = w3f[1] = w3f[2] = w3f[3] = (_Float16)0.0f;
        }
    }

    // ---- bias C-inits: C[row=4g+j][col=q] = bias[4g+j] ----
    f32x4 c1i, c2i, c3i;
    {
        float4 t = *reinterpret_cast<const float4*>(b1 + 4 * g);
        c1i[0] = t.x; c1i[1] = t.y; c1i[2] = t.z; c1i[3] = t.w;
        t = *reinterpret_cast<const float4*>(b2 + 4 * g);
        c2i[0] = t.x; c2i[1] = t.y; c2i[2] = t.z; c2i[3] = t.w;
        if (g < 2) {
            t = *reinterpret_cast<const float4*>(b3 + 4 * g);
            c3i[0] = t.x; c3i[1] = t.y; c3i[2] = t.z; c3i[3] = t.w;
        } else if (g == 2) {
            c3i[0] = b3[8]; c3i[1] = b3[9]; c3i[2] = 0.f; c3i[3] = 0.f;
        } else {
            c3i[0] = c3i[1] = c3i[2] = c3i[3] = 0.f;
        }
    }

    // ---- per-lane RNN affine coefficients for its two float2 loads ----
    // group 0: feats 0-3  = x0[0:4]            (identity, identity)
    // group 1: feats 4-7  = x0[4:6], cell0     (identity, cell0)
    // group 2: feats 8-11 = cell1, cell2
    // group 3: feats12-15 = cell3, cell4
    float a00, a01, a10, a11, bx0, by0;   // transform of v0
    float c00, c01, c10, c11, bx1, by1;   // transform of v1
    {
        const int cell0 = (g == 2) ? 1 : (g == 3) ? 3 : -1;
        const int cell1 = (g == 1) ? 0 : (g == 2) ? 2 : (g == 3) ? 4 : -1;
        if (cell0 >= 0) {
            float4 w = *reinterpret_cast<const float4*>(rnn_w2 + cell0 * 4);
            float2 bb = *reinterpret_cast<const float2*>(rnn_b2 + cell0 * 2);
            a00 = w.x; a01 = w.y; a10 = w.z; a11 = w.w; bx0 = bb.x; by0 = bb.y;
        } else {
            a00 = 1.f; a01 = 0.f; a10 = 0.f; a11 = 1.f; bx0 = 0.f; by0 = 0.f;
        }
        if (cell1 >= 0) {
            float4 w = *reinterpret_cast<const float4*>(rnn_w2 + cell1 * 4);
            float2 bb = *reinterpret_cast<const float2*>(rnn_b2 + cell1 * 2);
            c00 = w.x; c01 = w.y; c10 = w.z; c11 = w.w; bx1 = bb.x; by1 = bb.y;
        } else {
            c00 = 1.f; c01 = 0.f; c10 = 0.f; c11 = 1.f; bx1 = 0.f; by1 = 0.f;
        }
    }

    // ---- per-tile: build B-fragment, 3 chained MFMAs, park logits in LDS ----
#pragma unroll
    for (int t = 0; t < TILES; ++t) {
        const int row  = base + t * 16 + q;           // this lane's batch col
        const int rowc = min(row, B - 1);
        const size_t r6 = (size_t)rowc * 6;
        const float* xb0 = xs + lastOff + (size_t)rowc * 2;  // cell 0 ptr

        const float* p0 = (g == 0) ? x0 + r6
                        : (g == 1) ? x0 + r6 + 4
                        : (g == 2) ? xb0 + sB2
                                   : xb0 + 3 * sB2;
        const float* p1 = (g == 0) ? x0 + r6 + 2
                        : (g == 1) ? xb0
                        : (g == 2) ? xb0 + 2 * sB2
                                   : xb0 + 4 * sB2;
        const float2 v0 = *reinterpret_cast<const float2*>(p0);
        const float2 v1 = *reinterpret_cast<const float2*>(p1);

        const float f0 = fmaf(a00, v0.x, fmaf(a01, v0.y, bx0));
        const float f1 = fmaf(a10, v0.x, fmaf(a11, v0.y, by0));
        const float f2 = fmaf(c00, v1.x, fmaf(c01, v1.y, bx1));
        const float f3 = fmaf(c10, v1.x, fmaf(c11, v1.y, by1));

        half4 xbv;
        xbv[0] = (_Float16)f0; xbv[1] = (_Float16)f1;
        xbv[2] = (_Float16)f2; xbv[3] = (_Float16)f3;

        f32x4 d1 = __builtin_amdgcn_mfma_f32_16x16x16f16(w1f, xbv, c1i, 0, 0, 0);
        half4 h1v;
        h1v[0] = (_Float16)fmaxf(d1[0], 0.f); h1v[1] = (_Float16)fmaxf(d1[1], 0.f);
        h1v[2] = (_Float16)fmaxf(d1[2], 0.f); h1v[3] = (_Float16)fmaxf(d1[3], 0.f);

        f32x4 d2 = __builtin_amdgcn_mfma_f32_16x16x16f16(w2f, h1v, c2i, 0, 0, 0);
        half4 h2v;
        h2v[0] = (_Float16)fmaxf(d2[0], 0.f); h2v[1] = (_Float16)fmaxf(d2[1], 0.f);
        h2v[2] = (_Float16)fmaxf(d2[2], 0.f); h2v[3] = (_Float16)fmaxf(d2[3], 0.f);

        f32x4 d3 = __builtin_amdgcn_mfma_f32_16x16x16f16(w3f, h2v, c3i, 0, 0, 0);

        // logits[feat=4g+j][batch=q] -> sm[wid][t][q][4g+j]
        const int off = wid * (TILES * 320) + t * 320 + q * 20 + 4 * g;
        *reinterpret_cast<float4*>(sm + off) =
            make_float4(d3[0], d3[1], d3[2], d3[3]);
    }

    // ---- epilogue: one lane per batch row (lanes 0..TILES*16-1) ----
    // Intra-wave ds_write -> ds_read: compiler-inserted lgkmcnt orders it;
    // each wave touches only its own sm region, so no barrier needed.
    if (lane < TILES * 16) {
        const int off = wid * (TILES * 320) + (lane >> 4) * 320 + (lane & 15) * 20;
        const float4 L0 = *reinterpret_cast<const float4*>(sm + off);
        const float4 L1 = *reinterpret_cast<const float4*>(sm + off + 4);
        const float2 L2 = *reinterpret_cast<const float2*>(sm + off + 8);
        const float lg[10] = {L0.x, L0.y, L0.z, L0.w,
                              L1.x, L1.y, L1.z, L1.w,
                              L2.x, L2.y};
        float p[10];
        {
            float m = fmaxf(lg[0], lg[1]);
            float e0 = __expf(lg[0] - m), e1 = __expf(lg[1] - m);
            float inv = 1.0f / (e0 + e1);
            p[0] = e0 * inv; p[1] = e1 * inv;
        }
        {
            float m = fmaxf(fmaxf(lg[2], lg[3]), fmaxf(lg[4], lg[5]));
            float e2 = __expf(lg[2] - m), e3 = __expf(lg[3] - m);
            float e4 = __expf(lg[4] - m), e5 = __expf(lg[5] - m);
            float inv = 1.0f / (e2 + e3 + e4 + e5);
            p[2] = e2 * inv; p[3] = e3 * inv; p[4] = e4 * inv; p[5] = e5 * inv;
        }
        {
            float m = fmaxf(fmaxf(lg[6], lg[7]), fmaxf(lg[8], lg[9]));
            float e6 = __expf(lg[6] - m), e7 = __expf(lg[7] - m);
            float e8 = __expf(lg[8] - m), e9 = __expf(lg[9] - m);
            float inv = 1.0f / (e6 + e7 + e8 + e9);
            p[6] = e6 * inv; p[7] = e7 * inv; p[8] = e8 * inv; p[9] = e9 * inv;
        }
        const int grow = base + lane;   // == base + (lane>>4)*16 + (lane&15)
        if (grow < B) {
            float2* po = reinterpret_cast<float2*>(out + (size_t)grow * 10);
            po[0] = make_float2(p[0], p[1]);
            po[1] = make_float2(p[2], p[3]);
            po[2] = make_float2(p[4], p[5]);
            po[3] = make_float2(p[6], p[7]);
            po[4] = make_float2(p[8], p[9]);
        }
    }
}

extern "C" void kernel_launch(void* const* d_in, const int* in_sizes, int n_in,
                              void* d_out, int out_size, void* d_ws, size_t ws_size,
                              hipStream_t stream) {
    const float* x0     = (const float*)d_in[0];
    const float* xs     = (const float*)d_in[1];
    // d_in[2] = rnn_w1, d_in[3] = rnn_b1 -- dead code in the reference (DCE'd)
    const float* rnn_w2 = (const float*)d_in[4];
    const float* rnn_b2 = (const float*)d_in[5];
    const float* w1     = (const float*)d_in[6];
    const float* b1     = (const float*)d_in[7];
    const float* w2     = (const float*)d_in[8];
    const float* b2     = (const float*)d_in[9];
    const float* w3     = (const float*)d_in[10];
    const float* b3     = (const float*)d_in[11];

    const int B = in_sizes[0] / 6;                    // x0 is [B, 6]
    const int S = in_sizes[1] / (RCELLS * 2 * B);     // xs is [R, S, B, 2]
    const long long sB2     = (long long)S * B * 2;
    const long long lastOff = (long long)(S - 1) * B * 2;

    const int rowsPerBlock = TILES * 16 * 4;          // 128
    const int grid = (B + rowsPerBlock - 1) / rowsPerBlock;
    fused_model_mfma<<<grid, 256, 0, stream>>>(
        x0, xs, rnn_w2, rnn_b2, w1, b1, w2, b2, w3, b3,
        (float*)d_out, B, sB2, lastOff);
}